// Round 5
// baseline (2024.189 us; speedup 1.0000x reference)
//
#include <hip/hip_runtime.h>

// DUST_65085934403760 : LIHT sparse-coding + window attention, MI355X fp32.
// D=2048, BATCH=2048, P=8, OMEGA=50, 10 iters, L=1, CLAMP=150.
// Round 5 (numerics bit-identical to rounds 1/3/4):
//  - gemm_wp: 64x128 block tile -> 512 blocks = 2 blocks/CU = 2 waves/SIMD
//    (round-4 shipped 256 blocks = 1 wave/SIMD; no wave to hide latency).
//    Wave-private LDS double-buffer, ZERO __syncthreads, conflict-free swizzles.
//  - listep: fused spapply+topk (round-4, proven bit-exact slot order).

#define DD 2048
#define NB 2048

// ------------------------------------------------------------- GEMM (fp32)
// C[m,n] = sum_k A[m,k] * (TRANSB ? Bm[n,k] : Bm[k,n])  (+ Cadd[m,n] at end)
// 64x128 block tile, 256 thr (4 waves), wave w owns rows m0+16w..+15 with
// private double-buffered LDS. BK=8. Ascending-k single fma chain per output.
template<int TRANSB, int ADD>
__global__ __launch_bounds__(256)
void gemm_wp(const float* __restrict__ A, const float* __restrict__ Bm,
             const float* __restrict__ Cadd, float* __restrict__ Cout) {
  __shared__ float As[4][2][8][20];    //  5.1 KB (k-major, 16 rows + pad4)
  __shared__ float Bs[4][2][8][132];   // 33.8 KB
  const int tid = threadIdx.x, w = tid >> 6, lane = tid & 63;
  const int m0 = blockIdx.y * 64 + w * 16;
  const int n0 = blockIdx.x * 128;
  const int ty = lane >> 4, tx = lane & 15;   // thread tile: 4(m) x 8(n)

  // A staging (lanes 0..31): row m0 + (lane>>1), k-quad (lane&1)*4
  const int ar = (lane & 31) >> 1, ak = (lane & 1) * 4;
  const bool aload = lane < 32;
  const float* Ap = A + (size_t)(m0 + ar) * DD + ak;

  // B staging (all 64 lanes, 4 float4 each):
  //  TRANSB=0: k = (lane>>5) + 2r, n = (lane&31)*4, r=0..3
  //  TRANSB=1: rows n0+lane (2 float4) and n0+64+lane (2 float4)
  const int b0k = lane >> 5, b0n = (lane & 31) * 4;
  const float* Bp0  = Bm + (size_t)b0k * DD + n0 + b0n;
  const float* Bp1a = Bm + (size_t)(n0 + lane) * DD;
  const float* Bp1b = Bm + (size_t)(n0 + 64 + lane) * DD;

  float acc[4][8];
#pragma unroll
  for (int i = 0; i < 4; ++i)
#pragma unroll
    for (int j = 0; j < 8; ++j) acc[i][j] = 0.f;

  float4 apre, bpre0, bpre1, bpre2, bpre3;

  if (aload) apre = *(const float4*)Ap;
  if (TRANSB) {
    bpre0 = *(const float4*)(Bp1a);     bpre1 = *(const float4*)(Bp1a + 4);
    bpre2 = *(const float4*)(Bp1b);     bpre3 = *(const float4*)(Bp1b + 4);
  } else {
    bpre0 = *(const float4*)(Bp0);
    bpre1 = *(const float4*)(Bp0 + 2 * DD);
    bpre2 = *(const float4*)(Bp0 + 4 * DD);
    bpre3 = *(const float4*)(Bp0 + 6 * DD);
  }
  {
    float (*Aw)[20]  = As[w][0];
    float (*Bw)[132] = Bs[w][0];
    if (aload) {
      Aw[ak+0][ar] = apre.x; Aw[ak+1][ar] = apre.y;
      Aw[ak+2][ar] = apre.z; Aw[ak+3][ar] = apre.w;
    }
    if (TRANSB) {
      Bw[0][lane]=bpre0.x; Bw[1][lane]=bpre0.y; Bw[2][lane]=bpre0.z; Bw[3][lane]=bpre0.w;
      Bw[4][lane]=bpre1.x; Bw[5][lane]=bpre1.y; Bw[6][lane]=bpre1.z; Bw[7][lane]=bpre1.w;
      Bw[0][lane+64]=bpre2.x; Bw[1][lane+64]=bpre2.y; Bw[2][lane+64]=bpre2.z; Bw[3][lane+64]=bpre2.w;
      Bw[4][lane+64]=bpre3.x; Bw[5][lane+64]=bpre3.y; Bw[6][lane+64]=bpre3.z; Bw[7][lane+64]=bpre3.w;
    } else {
      *(float4*)&Bw[b0k  ][b0n] = bpre0;
      *(float4*)&Bw[b0k+2][b0n] = bpre1;
      *(float4*)&Bw[b0k+4][b0n] = bpre2;
      *(float4*)&Bw[b0k+6][b0n] = bpre3;
    }
  }

  const int NC = DD / 8;   // 256 chunks
  for (int c = 0; c < NC; ++c) {
    const int buf = c & 1;
    if (c + 1 < NC) {
      const int k1 = (c + 1) * 8;
      if (aload) apre = *(const float4*)(Ap + k1);
      if (TRANSB) {
        bpre0 = *(const float4*)(Bp1a + k1);     bpre1 = *(const float4*)(Bp1a + k1 + 4);
        bpre2 = *(const float4*)(Bp1b + k1);     bpre3 = *(const float4*)(Bp1b + k1 + 4);
      } else {
        const float* bp = Bp0 + (size_t)k1 * DD;
        bpre0 = *(const float4*)(bp);
        bpre1 = *(const float4*)(bp + 2 * DD);
        bpre2 = *(const float4*)(bp + 4 * DD);
        bpre3 = *(const float4*)(bp + 6 * DD);
      }
    }
    {
      float (*Aw)[20]  = As[w][buf];
      float (*Bw)[132] = Bs[w][buf];
#pragma unroll
      for (int kk = 0; kk < 8; ++kk) {
        float4 av  = *(const float4*)&Aw[kk][ty*4];
        float4 bv0 = *(const float4*)&Bw[kk][tx*4];
        float4 bv1 = *(const float4*)&Bw[kk][64 + tx*4];
        float a[4] = {av.x, av.y, av.z, av.w};
        float bb[8]= {bv0.x,bv0.y,bv0.z,bv0.w, bv1.x,bv1.y,bv1.z,bv1.w};
#pragma unroll
        for (int i = 0; i < 4; ++i)
#pragma unroll
          for (int j = 0; j < 8; ++j)
            acc[i][j] = fmaf(a[i], bb[j], acc[i][j]);
      }
    }
    if (c + 1 < NC) {
      float (*Aw)[20]  = As[w][buf ^ 1];
      float (*Bw)[132] = Bs[w][buf ^ 1];
      if (aload) {
        Aw[ak+0][ar] = apre.x; Aw[ak+1][ar] = apre.y;
        Aw[ak+2][ar] = apre.z; Aw[ak+3][ar] = apre.w;
      }
      if (TRANSB) {
        Bw[0][lane]=bpre0.x; Bw[1][lane]=bpre0.y; Bw[2][lane]=bpre0.z; Bw[3][lane]=bpre0.w;
        Bw[4][lane]=bpre1.x; Bw[5][lane]=bpre1.y; Bw[6][lane]=bpre1.z; Bw[7][lane]=bpre1.w;
        Bw[0][lane+64]=bpre2.x; Bw[1][lane+64]=bpre2.y; Bw[2][lane+64]=bpre2.z; Bw[3][lane+64]=bpre2.w;
        Bw[4][lane+64]=bpre3.x; Bw[5][lane+64]=bpre3.y; Bw[6][lane+64]=bpre3.z; Bw[7][lane+64]=bpre3.w;
      } else {
        *(float4*)&Bw[b0k  ][b0n] = bpre0;
        *(float4*)&Bw[b0k+2][b0n] = bpre1;
        *(float4*)&Bw[b0k+4][b0n] = bpre2;
        *(float4*)&Bw[b0k+6][b0n] = bpre3;
      }
    }
  }

#pragma unroll
  for (int i = 0; i < 4; ++i) {
    size_t row = (size_t)(m0 + ty*4 + i) * DD + n0;
    float4 c0 = {acc[i][0], acc[i][1], acc[i][2], acc[i][3]};
    float4 c1 = {acc[i][4], acc[i][5], acc[i][6], acc[i][7]};
    if (ADD) {
      float4 d0 = *(const float4*)&Cadd[row + tx*4];
      float4 d1 = *(const float4*)&Cadd[row + 64 + tx*4];
      c0.x+=d0.x; c0.y+=d0.y; c0.z+=d0.z; c0.w+=d0.w;
      c1.x+=d1.x; c1.y+=d1.y; c1.z+=d1.z; c1.w+=d1.w;
    }
    *(float4*)&Cout[row + tx*4]      = c0;
    *(float4*)&Cout[row + 64 + tx*4] = c1;
  }
}

// ------------------------------------------------------------ top-k (1 wave)
__global__ __launch_bounds__(64)
void topk_kernel(const float* __restrict__ src, unsigned* __restrict__ sidx,
                 float* __restrict__ sval, int* __restrict__ scnt,
                 float* __restrict__ dense, float* __restrict__ mD,
                 int finalMode) {
  const int b = blockIdx.x;
  const int lane = threadIdx.x;
  const float* row = src + (size_t)b * DD;
  float v[32]; unsigned ab[32];
#pragma unroll
  for (int e4 = 0; e4 < 8; ++e4) {
    float4 t = *(const float4*)&row[e4*256 + lane*4];
    v[e4*4+0]=t.x; v[e4*4+1]=t.y; v[e4*4+2]=t.z; v[e4*4+3]=t.w;
  }
#pragma unroll
  for (int e = 0; e < 32; ++e) ab[e] = __float_as_uint(v[e]) & 0x7fffffffu;

  unsigned mxb = 0;
#pragma unroll
  for (int e = 0; e < 32; ++e) mxb = ab[e] > mxb ? ab[e] : mxb;
  for (int off = 32; off; off >>= 1) {
    unsigned o = (unsigned)__shfl_down((int)mxb, off);
    mxb = o > mxb ? o : mxb;
  }
  mxb = (unsigned)__shfl((int)mxb, 0);
  const int emax = (int)(mxb >> 23);

  int eStar = 0, cntAbove = 0;
  {
    int prevc = 0;
    for (int e = emax; e >= 0; --e) {
      unsigned T = ((unsigned)e) << 23;
      int c = 0;
#pragma unroll
      for (int k = 0; k < 32; ++k) c += (ab[k] >= T) ? 1 : 0;
      for (int off = 32; off; off >>= 1) c += __shfl_down(c, off);
      c = __shfl(c, 0);
      if (c >= 50) { eStar = e; cntAbove = prevc; break; }
      prevc = c;
    }
  }
  unsigned kth = ((unsigned)eStar) << 23;
  int kneed = 50 - cntAbove;

  __shared__ int hist[256];
  __shared__ int sh_sel, sh_kneed;
  for (int p = 0; p < 3; ++p) {
    const unsigned mask = (p==0) ? 0x7F800000u : (p==1) ? 0x7FFF8000u : 0x7FFFFF80u;
    const int sh = (p==0) ? 15 : (p==1) ? 7 : 0;
    for (int t = lane; t < 256; t += 64) hist[t] = 0;
    __syncthreads();
#pragma unroll
    for (int e = 0; e < 32; ++e)
      if ((ab[e] & mask) == kth) atomicAdd(&hist[(ab[e] >> sh) & 0xFF], 1);
    __syncthreads();
    int h0 = hist[lane*4+0], h1 = hist[lane*4+1], h2 = hist[lane*4+2], h3 = hist[lane*4+3];
    int s = h0 + h1 + h2 + h3;
    int x = s;
    for (int off = 1; off < 64; off <<= 1) {
      int y = __shfl_down(x, off);
      if (lane + off < 64) x += y;
    }
    int excl = x - s;
    int c3 = excl + h3, c2 = c3 + h2, c1 = c2 + h1, c0 = c1 + h0;
    if (c0 >= kneed && c1   < kneed) { sh_sel = lane*4+0; sh_kneed = kneed - c1;  }
    if (c1 >= kneed && c2   < kneed) { sh_sel = lane*4+1; sh_kneed = kneed - c2;  }
    if (c2 >= kneed && c3   < kneed) { sh_sel = lane*4+2; sh_kneed = kneed - c3;  }
    if (c3 >= kneed && excl < kneed) { sh_sel = lane*4+3; sh_kneed = kneed - excl;}
    __syncthreads();
    kth |= ((unsigned)sh_sel) << sh;
    kneed = sh_kneed;
    __syncthreads();
  }

  int base = 0;
#pragma unroll
  for (int e4 = 0; e4 < 8; ++e4) {
    float o[4];
#pragma unroll
    for (int qq = 0; qq < 4; ++qq) {
      const int e = e4*4 + qq;
      const bool sel = ab[e] >= kth;
      unsigned long long msk = __ballot(sel);
      int pre = __popcll(msk & ((1ull << lane) - 1ull));
      const unsigned gi = (unsigned)(e4*256 + lane*4 + qq);
      if (sel) {
        int slot = base + pre;
        if (slot < 64) { sidx[b*64+slot] = gi; sval[b*64+slot] = v[e]; }
        if (finalMode) atomicAdd(&mD[gi & 1023u], v[e]*v[e]);
      }
      base += __popcll(msk);
      o[qq] = sel ? v[e] : 0.f;
    }
    if (finalMode) {
      float4 t = {o[0],o[1],o[2],o[3]};
      *(float4*)&dense[(size_t)b*DD + e4*256 + lane*4] = t;
    }
  }
  if (lane == 0) scnt[b] = base < 64 ? base : 64;
}

// ---------------------------------------------- fused spapply + topk (1 row)
__global__ __launch_bounds__(256)
void listep_kernel(const float* __restrict__ M, const float* __restrict__ baseB,
                   unsigned* __restrict__ sidx, float* __restrict__ sval,
                   int* __restrict__ scnt, float* __restrict__ dense,
                   float* __restrict__ mD, int finalMode) {
  const int b = blockIdx.x, tid = threadIdx.x;
  const int w = tid >> 6, lane = tid & 63;
  __shared__ unsigned si[64]; __shared__ float sv[64]; __shared__ int snc;
  __shared__ int hist[256];
  __shared__ unsigned redu[4]; __shared__ int redi[8];
  __shared__ int sh_sel, sh_kneed;
  if (tid < 64) { si[tid] = sidx[b*64+tid]; sv[tid] = sval[b*64+tid]; }
  if (tid == 0) snc = scnt[b];
  __syncthreads();
  const int nc = snc;
  const size_t o4 = (size_t)b * 512 + tid;
  float4 a0 = ((const float4*)baseB)[o4];
  float4 a1 = ((const float4*)baseB)[o4 + 256];
  int t = 0;
  for (; t + 2 <= nc; t += 2) {
    unsigned j0 = si[t], j1 = si[t+1];
    float v0 = sv[t], v1 = sv[t+1];
    const float4* r0 = (const float4*)(M + (size_t)j0 * DD);
    const float4* r1 = (const float4*)(M + (size_t)j1 * DD);
    float4 m00 = r0[tid], m01 = r0[tid + 256];
    float4 m10 = r1[tid], m11 = r1[tid + 256];
    a0.x = fmaf(v0, m00.x, a0.x); a0.y = fmaf(v0, m00.y, a0.y);
    a0.z = fmaf(v0, m00.z, a0.z); a0.w = fmaf(v0, m00.w, a0.w);
    a1.x = fmaf(v0, m01.x, a1.x); a1.y = fmaf(v0, m01.y, a1.y);
    a1.z = fmaf(v0, m01.z, a1.z); a1.w = fmaf(v0, m01.w, a1.w);
    a0.x = fmaf(v1, m10.x, a0.x); a0.y = fmaf(v1, m10.y, a0.y);
    a0.z = fmaf(v1, m10.z, a0.z); a0.w = fmaf(v1, m10.w, a0.w);
    a1.x = fmaf(v1, m11.x, a1.x); a1.y = fmaf(v1, m11.y, a1.y);
    a1.z = fmaf(v1, m11.z, a1.z); a1.w = fmaf(v1, m11.w, a1.w);
  }
  if (t < nc) {
    unsigned j0 = si[t]; float v0 = sv[t];
    const float4* r0 = (const float4*)(M + (size_t)j0 * DD);
    float4 m00 = r0[tid], m01 = r0[tid + 256];
    a0.x = fmaf(v0, m00.x, a0.x); a0.y = fmaf(v0, m00.y, a0.y);
    a0.z = fmaf(v0, m00.z, a0.z); a0.w = fmaf(v0, m00.w, a0.w);
    a1.x = fmaf(v0, m01.x, a1.x); a1.y = fmaf(v0, m01.y, a1.y);
    a1.z = fmaf(v0, m01.z, a1.z); a1.w = fmaf(v0, m01.w, a1.w);
  }
  float v0a[4] = {a0.x, a0.y, a0.z, a0.w};
  float v1a[4] = {a1.x, a1.y, a1.z, a1.w};
  unsigned ab0[4], ab1[4];
#pragma unroll
  for (int q = 0; q < 4; ++q) {
    ab0[q] = __float_as_uint(v0a[q]) & 0x7fffffffu;
    ab1[q] = __float_as_uint(v1a[q]) & 0x7fffffffu;
  }
  unsigned mx = 0;
#pragma unroll
  for (int q = 0; q < 4; ++q) {
    mx = ab0[q] > mx ? ab0[q] : mx;
    mx = ab1[q] > mx ? ab1[q] : mx;
  }
  for (int off = 32; off; off >>= 1) {
    unsigned o = (unsigned)__shfl_down((int)mx, off);
    mx = o > mx ? o : mx;
  }
  if (lane == 0) redu[w] = mx;
  __syncthreads();
  mx = redu[0];
  mx = redu[1] > mx ? redu[1] : mx;
  mx = redu[2] > mx ? redu[2] : mx;
  mx = redu[3] > mx ? redu[3] : mx;
  const int emax = (int)(mx >> 23);

  int eStar = 0, cntAbove = 0;
  {
    int prevc = 0;
    for (int e = emax; e >= 0; --e) {
      unsigned T = ((unsigned)e) << 23;
      int c = 0;
#pragma unroll
      for (int q = 0; q < 4; ++q) {
        c += (ab0[q] >= T) ? 1 : 0;
        c += (ab1[q] >= T) ? 1 : 0;
      }
      for (int off = 32; off; off >>= 1) c += __shfl_down(c, off);
      if (lane == 0) redi[w] = c;
      __syncthreads();
      c = redi[0] + redi[1] + redi[2] + redi[3];
      __syncthreads();
      if (c >= 50) { eStar = e; cntAbove = prevc; break; }
      prevc = c;
    }
  }
  unsigned kth = ((unsigned)eStar) << 23;
  int kneed = 50 - cntAbove;

  for (int p = 0; p < 3; ++p) {
    const unsigned mask = (p==0) ? 0x7F800000u : (p==1) ? 0x7FFF8000u : 0x7FFFFF80u;
    const int sh = (p==0) ? 15 : (p==1) ? 7 : 0;
    hist[tid] = 0;
    __syncthreads();
#pragma unroll
    for (int q = 0; q < 4; ++q) {
      if ((ab0[q] & mask) == kth) atomicAdd(&hist[(ab0[q] >> sh) & 0xFF], 1);
      if ((ab1[q] & mask) == kth) atomicAdd(&hist[(ab1[q] >> sh) & 0xFF], 1);
    }
    __syncthreads();
    if (w == 0) {
      int h0 = hist[lane*4+0], h1 = hist[lane*4+1], h2 = hist[lane*4+2], h3 = hist[lane*4+3];
      int s = h0 + h1 + h2 + h3;
      int x = s;
      for (int off = 1; off < 64; off <<= 1) {
        int y = __shfl_down(x, off);
        if (lane + off < 64) x += y;
      }
      int excl = x - s;
      int c3 = excl + h3, c2 = c3 + h2, c1 = c2 + h1, c0 = c1 + h0;
      if (c0 >= kneed && c1   < kneed) { sh_sel = lane*4+0; sh_kneed = kneed - c1;  }
      if (c1 >= kneed && c2   < kneed) { sh_sel = lane*4+1; sh_kneed = kneed - c2;  }
      if (c2 >= kneed && c3   < kneed) { sh_sel = lane*4+2; sh_kneed = kneed - c3;  }
      if (c3 >= kneed && excl < kneed) { sh_sel = lane*4+3; sh_kneed = kneed - excl;}
    }
    __syncthreads();
    kth |= ((unsigned)sh_sel) << sh;
    kneed = sh_kneed;
    __syncthreads();
  }

  unsigned long long m0q[4], m1q[4];
  int q0pre[4], q1pre[4], c0 = 0, c1 = 0;
#pragma unroll
  for (int q = 0; q < 4; ++q) {
    m0q[q] = __ballot(ab0[q] >= kth);
    q0pre[q] = c0; c0 += __popcll(m0q[q]);
  }
#pragma unroll
  for (int q = 0; q < 4; ++q) {
    m1q[q] = __ballot(ab1[q] >= kth);
    q1pre[q] = c1; c1 += __popcll(m1q[q]);
  }
  if (lane == 0) { redi[w] = c0; redi[4 + w] = c1; }
  __syncthreads();
  int bs[8]; int run = 0;
#pragma unroll
  for (int c = 0; c < 8; ++c) { bs[c] = run; run += redi[c]; }
  const int total = run;
  const unsigned long long ltm = (1ull << lane) - 1ull;
  float o0[4], o1[4];
#pragma unroll
  for (int q = 0; q < 4; ++q) {
    const bool sel = ab0[q] >= kth;
    if (sel) {
      int slot = bs[w] + q0pre[q] + __popcll(m0q[q] & ltm);
      const unsigned gi = (unsigned)(tid*4 + q);
      if (slot < 64) { sidx[b*64+slot] = gi; sval[b*64+slot] = v0a[q]; }
      if (finalMode) atomicAdd(&mD[gi & 1023u], v0a[q]*v0a[q]);
    }
    o0[q] = sel ? v0a[q] : 0.f;
  }
#pragma unroll
  for (int q = 0; q < 4; ++q) {
    const bool sel = ab1[q] >= kth;
    if (sel) {
      int slot = bs[4 + w] + q1pre[q] + __popcll(m1q[q] & ltm);
      const unsigned gi = (unsigned)(1024 + tid*4 + q);
      if (slot < 64) { sidx[b*64+slot] = gi; sval[b*64+slot] = v1a[q]; }
      if (finalMode) atomicAdd(&mD[gi & 1023u], v1a[q]*v1a[q]);
    }
    o1[q] = sel ? v1a[q] : 0.f;
  }
  if (finalMode) {
    float4 t0 = {o0[0], o0[1], o0[2], o0[3]};
    float4 t1 = {o1[0], o1[1], o1[2], o1[3]};
    ((float4*)dense)[o4] = t0;
    ((float4*)dense)[o4 + 256] = t1;
  }
  if (tid == 0) scnt[b] = total < 64 ? total : 64;
}

// -------------------------------------------- sparse apply (dense out, no base)
__global__ __launch_bounds__(256)
void spapply2(const float* __restrict__ M, float* __restrict__ outF,
              const unsigned* __restrict__ sidx, const float* __restrict__ sval,
              const int* __restrict__ scnt) {
  const int b = blockIdx.x, tid = threadIdx.x;
  __shared__ unsigned si[64]; __shared__ float sv[64]; __shared__ int snc;
  if (tid < 64) { si[tid] = sidx[b*64+tid]; sv[tid] = sval[b*64+tid]; }
  if (tid == 0) snc = scnt[b];
  __syncthreads();
  const int nc = snc;
  const size_t o4 = (size_t)b * 512 + tid;
  float4 a0 = make_float4(0.f,0.f,0.f,0.f);
  float4 a1 = make_float4(0.f,0.f,0.f,0.f);
  int t = 0;
  for (; t + 2 <= nc; t += 2) {
    unsigned j0 = si[t], j1 = si[t+1];
    float v0 = sv[t], v1 = sv[t+1];
    const float4* r0 = (const float4*)(M + (size_t)j0 * DD);
    const float4* r1 = (const float4*)(M + (size_t)j1 * DD);
    float4 m00 = r0[tid], m01 = r0[tid + 256];
    float4 m10 = r1[tid], m11 = r1[tid + 256];
    a0.x = fmaf(v0, m00.x, a0.x); a0.y = fmaf(v0, m00.y, a0.y);
    a0.z = fmaf(v0, m00.z, a0.z); a0.w = fmaf(v0, m00.w, a0.w);
    a1.x = fmaf(v0, m01.x, a1.x); a1.y = fmaf(v0, m01.y, a1.y);
    a1.z = fmaf(v0, m01.z, a1.z); a1.w = fmaf(v0, m01.w, a1.w);
    a0.x = fmaf(v1, m10.x, a0.x); a0.y = fmaf(v1, m10.y, a0.y);
    a0.z = fmaf(v1, m10.z, a0.z); a0.w = fmaf(v1, m10.w, a0.w);
    a1.x = fmaf(v1, m11.x, a1.x); a1.y = fmaf(v1, m11.y, a1.y);
    a1.z = fmaf(v1, m11.z, a1.z); a1.w = fmaf(v1, m11.w, a1.w);
  }
  if (t < nc) {
    unsigned j0 = si[t]; float v0 = sv[t];
    const float4* r0 = (const float4*)(M + (size_t)j0 * DD);
    float4 m00 = r0[tid], m01 = r0[tid + 256];
    a0.x = fmaf(v0, m00.x, a0.x); a0.y = fmaf(v0, m00.y, a0.y);
    a0.z = fmaf(v0, m00.z, a0.z); a0.w = fmaf(v0, m00.w, a0.w);
    a1.x = fmaf(v0, m01.x, a1.x); a1.y = fmaf(v0, m01.y, a1.y);
    a1.z = fmaf(v0, m01.z, a1.z); a1.w = fmaf(v0, m01.w, a1.w);
  }
  ((float4*)outF)[o4] = a0;
  ((float4*)outF)[o4 + 256] = a1;
}

// ------------------------------------------------------------- attention bits
__global__ __launch_bounds__(256)
void attdot_kernel(const float* __restrict__ prev, const float* __restrict__ U,
                   float* __restrict__ att) {
  const int b = blockIdx.x, p = blockIdx.y, tid = threadIdx.x;
  const float* pr = prev + ((size_t)p*NB + b) * DD;
  const float* u  = U + (size_t)b * DD;
  float s = 0.f;
#pragma unroll
  for (int h = 0; h < 2; ++h) {
    int i = (tid + h*256) * 4;
    float4 a = *(const float4*)&pr[i];
    float4 c = *(const float4*)&u[i];
    s += a.x*c.x + a.y*c.y + a.z*c.z + a.w*c.w;
  }
  for (int off = 32; off; off >>= 1) s += __shfl_down(s, off);
  __shared__ float ps[4];
  if ((tid & 63) == 0) ps[tid >> 6] = s;
  __syncthreads();
  if (tid == 0) att[(size_t)p*NB + b] = ps[0]+ps[1]+ps[2]+ps[3];
}

__global__ __launch_bounds__(256)
void softmax_kernel(const float* __restrict__ att, float* __restrict__ attw) {
  const int p = blockIdx.x, tid = threadIdx.x;
  const float* a = att + (size_t)p*NB;
  float loc[8]; float mx = -3.4e38f;
#pragma unroll
  for (int h = 0; h < 8; ++h) { loc[h] = a[tid + h*256]; mx = fmaxf(mx, loc[h]); }
  for (int off = 32; off; off >>= 1) mx = fmaxf(mx, __shfl_down(mx, off));
  __shared__ float ps[4]; __shared__ float sh_m, sh_s;
  if ((tid & 63) == 0) ps[tid >> 6] = mx;
  __syncthreads();
  if (tid == 0) sh_m = fmaxf(fmaxf(ps[0],ps[1]), fmaxf(ps[2],ps[3]));
  __syncthreads();
  const float m = sh_m;
  float sum = 0.f;
#pragma unroll
  for (int h = 0; h < 8; ++h) sum += expf(loc[h] - m);
  for (int off = 32; off; off >>= 1) sum += __shfl_down(sum, off);
  __syncthreads();
  if ((tid & 63) == 0) ps[tid >> 6] = sum;
  __syncthreads();
  if (tid == 0) sh_s = ps[0]+ps[1]+ps[2]+ps[3];
  __syncthreads();
  const float inv = 1.0f / sh_s;
#pragma unroll
  for (int h = 0; h < 8; ++h) attw[(size_t)p*NB + tid + h*256] = expf(loc[h] - m) * inv;
}

__global__ __launch_bounds__(256)
void zatt_kernel(const float* __restrict__ prev, const float* __restrict__ attw,
                 const float* __restrict__ lam, float* __restrict__ Z) {
  const int b = blockIdx.x, tid = threadIdx.x;
  __shared__ float w[8];
  if (tid < 8) w[tid] = attw[(size_t)tid*NB + b];
  __syncthreads();
  const float l2 = lam[0];
#pragma unroll
  for (int h = 0; h < 2; ++h) {
    int i = (tid + h*256) * 4;
    float4 acc = {0.f,0.f,0.f,0.f};
#pragma unroll
    for (int p = 0; p < 8; ++p) {
      float4 pv = *(const float4*)&prev[((size_t)p*NB + b)*DD + i];
      float wp = w[p];
      acc.x += wp * fminf(fmaxf(pv.x, -150.f), 150.f);
      acc.y += wp * fminf(fmaxf(pv.y, -150.f), 150.f);
      acc.z += wp * fminf(fmaxf(pv.z, -150.f), 150.f);
      acc.w += wp * fminf(fmaxf(pv.w, -150.f), 150.f);
    }
    acc.x *= l2; acc.y *= l2; acc.z *= l2; acc.w *= l2;
    *(float4*)&Z[(size_t)b*DD + i] = acc;
  }
}

__global__ __launch_bounds__(256)
void norm_kernel(float* __restrict__ mD) {
  const int tid = threadIdx.x;
  float v[4]; float mn = 3.4e38f, mx = -3.4e38f;
#pragma unroll
  for (int h = 0; h < 4; ++h) {
    v[h] = mD[tid + h*256];
    mn = fminf(mn, v[h]); mx = fmaxf(mx, v[h]);
  }
  for (int off = 32; off; off >>= 1) {
    mn = fminf(mn, __shfl_down(mn, off));
    mx = fmaxf(mx, __shfl_down(mx, off));
  }
  __shared__ float pmn[4], pmx[4]; __shared__ float smn, smx;
  if ((tid & 63) == 0) { pmn[tid>>6] = mn; pmx[tid>>6] = mx; }
  __syncthreads();
  if (tid == 0) {
    smn = fminf(fminf(pmn[0],pmn[1]), fminf(pmn[2],pmn[3]));
    smx = fmaxf(fmaxf(pmx[0],pmx[1]), fmaxf(pmx[2],pmx[3]));
  }
  __syncthreads();
  const float d = smx - smn + 1e-8f;
#pragma unroll
  for (int h = 0; h < 4; ++h) mD[tid + h*256] = (v[h] - smn) / d;
}

// ----------------------------------------------------------------- launcher
extern "C" void kernel_launch(void* const* d_in, const int* in_sizes, int n_in,
                              void* d_out, int out_size, void* d_ws, size_t ws_size,
                              hipStream_t stream) {
  const float* x    = (const float*)d_in[0];   // (2048, 2048)
  const float* prev = (const float*)d_in[1];   // (8, 2048, 2048)
  const float* Wd   = (const float*)d_in[2];   // (2048, 2048)
  const float* S    = (const float*)d_in[3];   // (2048, 2048) symmetric
  const float* lam  = (const float*)d_in[4];   // scalar

  float* out   = (float*)d_out;
  float* mD    = out;
  float* zlast = out + 1024;

  float* B  = (float*)d_ws;                       // 16 MB
  float* C  = B  + (1u << 22);                    // 16 MB
  float* X1 = C  + (1u << 22);                    // 16 MB
  unsigned* sidx = (unsigned*)(X1 + (1u << 22));
  float*    sval = (float*)(sidx + 2048*64);
  int*      scnt = (int*)(sval + 2048*64);
  float*    att  = (float*)(scnt + 2048);
  float*    attw = att + 8*2048;
  float*    U    = zlast;

  const dim3 gGemm(DD/128, DD/64);    // (16, 32) = 512 blocks (2/CU)

  // B = x @ Wd^T
  gemm_wp<1,0><<<gGemm, 256, 0, stream>>>(x, Wd, nullptr, B);
  // z1 = hard_thr(B)
  topk_kernel<<<NB, 64, 0, stream>>>(B, sidx, sval, scnt, nullptr, nullptr, 0);
  // z2 = hard_thr(B + S z1)   (fused)
  listep_kernel<<<NB, 256, 0, stream>>>(S, B, sidx, sval, scnt, nullptr, nullptr, 0);
  // s_t = Wd^T z2  (sparse rows of Wd)
  spapply2<<<NB, 256, 0, stream>>>(Wd, X1, sidx, sval, scnt);
  // u = s_t @ Wd
  gemm_wp<0,0><<<gGemm, 256, 0, stream>>>(X1, Wd, nullptr, U);
  // att / softmax / z_att
  attdot_kernel<<<dim3(NB, 8), 256, 0, stream>>>(prev, U, att);
  softmax_kernel<<<8, 256, 0, stream>>>(att, attw);
  zatt_kernel<<<NB, 256, 0, stream>>>(prev, attw, lam, X1);
  // iter 1 (dense z): C = B + z_att @ S
  gemm_wp<0,1><<<gGemm, 256, 0, stream>>>(X1, S, B, C);
  topk_kernel<<<NB, 64, 0, stream>>>(C, sidx, sval, scnt, nullptr, nullptr, 0);
  for (int it = 1; it < 10; ++it) {
    const int fin = (it == 9);
    if (fin) hipMemsetAsync(mD, 0, 1024 * sizeof(float), stream);
    listep_kernel<<<NB, 256, 0, stream>>>(S, B, sidx, sval, scnt,
                                          fin ? zlast : nullptr,
                                          fin ? mD : nullptr, fin);
  }
  norm_kernel<<<1, 256, 0, stream>>>(mD);
}

// Round 6
// 1831.709 us; speedup vs baseline: 1.1051x; 1.1051x over previous
//
#include <hip/hip_runtime.h>

// DUST_65085934403760 : LIHT sparse-coding + window attention, MI355X fp32.
// D=2048, BATCH=2048, P=8, OMEGA=50, 10 iters, L=1, CLAMP=150.
// Round 6 (numerics bit-identical to rounds 1/3/4/5):
//  - gemm_sb: SGPR-B GEMM. Wave = 64 m-rows x 16 n-cols; B'[k][n-chunk] is
//    wave-uniform -> s_load (scalar cache) feeding v_fmac vacc, s_b, v_a.
//    LDS carries only A (1 ds_read_b32/k/wave = 0.125 B/fma) -> LDS demand
//    finally under the VALU wall. 4 blocks/CU, 16 waves/CU.
//  - All GEMMs NN with n-contiguous B: GEMM1 uses pre-transposed WdT (wtrans),
//    GEMM2 uses Wd, GEMM3 uses S (symmetric -> bitwise-equal rows).
//  - listep/topk/spapply/attention: round-5 proven kernels, unchanged.

#define DD 2048
#define NB 2048

// ------------------------------------------------------- transpose (Wd -> WdT)
__global__ __launch_bounds__(256)
void wtrans(const float* __restrict__ W, float* __restrict__ WT) {
  __shared__ float t[32][33];
  const int tid = threadIdx.x, tx = tid & 31, ty = tid >> 5;  // ty 0..7
  const int c0 = blockIdx.x * 32, r0 = blockIdx.y * 32;
#pragma unroll
  for (int p = 0; p < 4; ++p)
    t[ty + 8*p][tx] = W[(size_t)(r0 + ty + 8*p) * DD + c0 + tx];
  __syncthreads();
#pragma unroll
  for (int p = 0; p < 4; ++p)
    WT[(size_t)(c0 + ty + 8*p) * DD + r0 + tx] = t[tx][ty + 8*p];
}

// ------------------------------------------------------------- GEMM (fp32)
// C[m,n] = sum_k A[m,k] * Bn[k,n] (+ Cadd[m,n] at end). Bn row-major [k][n].
// Block: 256 thr = 4 waves sharing a 64-row A tile (LDS, double-buffered,
// 1 barrier / 64-k chunk). Wave w covers cols nb..nb+15 (wave-uniform ->
// scalar loads). Lane = m-row. acc[16]. Ascending-k single fma chain.
template<int ADD>
__global__ __launch_bounds__(256)
void gemm_sb(const float* __restrict__ A, const float* __restrict__ Bn,
             const float* __restrict__ Cadd, float* __restrict__ Cout) {
  __shared__ float As[2][64][65];   // 33.3 KB, [buf][k][m] (+1 pad)
  const int tid = threadIdx.x, w = tid >> 6, lane = tid & 63;
  const int m0 = blockIdx.y * 64;
  const int nb = __builtin_amdgcn_readfirstlane((int)(blockIdx.x * 64) + w * 16);
  const float* Bu = Bn + nb;        // wave-uniform base -> SGPR

  // A staging: thread t loads row (t>>2), k-quad base (t&3)*16 (16 floats).
  const int sr = tid >> 2, sk = (tid & 3) * 16;
  const float* Ap = A + (size_t)(m0 + sr) * DD + sk;

  float acc[16];
#pragma unroll
  for (int j = 0; j < 16; ++j) acc[j] = 0.f;

  // stage chunk 0 into buf 0
  {
    float4 v0 = *(const float4*)(Ap + 0);
    float4 v1 = *(const float4*)(Ap + 4);
    float4 v2 = *(const float4*)(Ap + 8);
    float4 v3 = *(const float4*)(Ap + 12);
    float fv[16] = {v0.x,v0.y,v0.z,v0.w, v1.x,v1.y,v1.z,v1.w,
                    v2.x,v2.y,v2.z,v2.w, v3.x,v3.y,v3.z,v3.w};
#pragma unroll
    for (int i = 0; i < 16; ++i) As[0][sk + i][sr] = fv[i];
  }
  __syncthreads();

  const int NC = DD / 64;   // 32 chunks
  for (int c = 0; c < NC; ++c) {
    const int buf = c & 1;
    float4 p0, p1, p2, p3;
    if (c + 1 < NC) {
      const float* ap = Ap + (c + 1) * 64;
      p0 = *(const float4*)(ap + 0);
      p1 = *(const float4*)(ap + 4);
      p2 = *(const float4*)(ap + 8);
      p3 = *(const float4*)(ap + 12);
    }
    // compute 64 k-steps on As[buf]
    {
      const float (*Aw)[65] = As[buf];
      const float* Bk = Bu + (size_t)(c * 64) * DD;
#pragma unroll 8
      for (int kk = 0; kk < 64; ++kk) {
        float a = Aw[kk][lane];
        const float* bp = Bk + (size_t)kk * DD;
        float4 b0 = *(const float4*)(bp + 0);
        float4 b1 = *(const float4*)(bp + 4);
        float4 b2 = *(const float4*)(bp + 8);
        float4 b3 = *(const float4*)(bp + 12);
        acc[ 0] = fmaf(a, b0.x, acc[ 0]);
        acc[ 1] = fmaf(a, b0.y, acc[ 1]);
        acc[ 2] = fmaf(a, b0.z, acc[ 2]);
        acc[ 3] = fmaf(a, b0.w, acc[ 3]);
        acc[ 4] = fmaf(a, b1.x, acc[ 4]);
        acc[ 5] = fmaf(a, b1.y, acc[ 5]);
        acc[ 6] = fmaf(a, b1.z, acc[ 6]);
        acc[ 7] = fmaf(a, b1.w, acc[ 7]);
        acc[ 8] = fmaf(a, b2.x, acc[ 8]);
        acc[ 9] = fmaf(a, b2.y, acc[ 9]);
        acc[10] = fmaf(a, b2.z, acc[10]);
        acc[11] = fmaf(a, b2.w, acc[11]);
        acc[12] = fmaf(a, b3.x, acc[12]);
        acc[13] = fmaf(a, b3.y, acc[13]);
        acc[14] = fmaf(a, b3.z, acc[14]);
        acc[15] = fmaf(a, b3.w, acc[15]);
      }
    }
    if (c + 1 < NC) {
      float fv[16] = {p0.x,p0.y,p0.z,p0.w, p1.x,p1.y,p1.z,p1.w,
                      p2.x,p2.y,p2.z,p2.w, p3.x,p3.y,p3.z,p3.w};
      float (*An)[65] = As[buf ^ 1];
#pragma unroll
      for (int i = 0; i < 16; ++i) An[sk + i][sr] = fv[i];
      __syncthreads();
    }
  }

  // epilogue: lane owns row m0+lane, cols nb..nb+15
  {
    size_t row = (size_t)(m0 + lane) * DD + nb;
    float4 c0 = {acc[ 0], acc[ 1], acc[ 2], acc[ 3]};
    float4 c1 = {acc[ 4], acc[ 5], acc[ 6], acc[ 7]};
    float4 c2 = {acc[ 8], acc[ 9], acc[10], acc[11]};
    float4 c3 = {acc[12], acc[13], acc[14], acc[15]};
    if (ADD) {
      float4 d0 = *(const float4*)&Cadd[row + 0];
      float4 d1 = *(const float4*)&Cadd[row + 4];
      float4 d2 = *(const float4*)&Cadd[row + 8];
      float4 d3 = *(const float4*)&Cadd[row + 12];
      c0.x+=d0.x; c0.y+=d0.y; c0.z+=d0.z; c0.w+=d0.w;
      c1.x+=d1.x; c1.y+=d1.y; c1.z+=d1.z; c1.w+=d1.w;
      c2.x+=d2.x; c2.y+=d2.y; c2.z+=d2.z; c2.w+=d2.w;
      c3.x+=d3.x; c3.y+=d3.y; c3.z+=d3.z; c3.w+=d3.w;
    }
    *(float4*)&Cout[row + 0]  = c0;
    *(float4*)&Cout[row + 4]  = c1;
    *(float4*)&Cout[row + 8]  = c2;
    *(float4*)&Cout[row + 12] = c3;
  }
}

// ------------------------------------------------------------ top-k (1 wave)
__global__ __launch_bounds__(64)
void topk_kernel(const float* __restrict__ src, unsigned* __restrict__ sidx,
                 float* __restrict__ sval, int* __restrict__ scnt,
                 float* __restrict__ dense, float* __restrict__ mD,
                 int finalMode) {
  const int b = blockIdx.x;
  const int lane = threadIdx.x;
  const float* row = src + (size_t)b * DD;
  float v[32]; unsigned ab[32];
#pragma unroll
  for (int e4 = 0; e4 < 8; ++e4) {
    float4 t = *(const float4*)&row[e4*256 + lane*4];
    v[e4*4+0]=t.x; v[e4*4+1]=t.y; v[e4*4+2]=t.z; v[e4*4+3]=t.w;
  }
#pragma unroll
  for (int e = 0; e < 32; ++e) ab[e] = __float_as_uint(v[e]) & 0x7fffffffu;

  unsigned mxb = 0;
#pragma unroll
  for (int e = 0; e < 32; ++e) mxb = ab[e] > mxb ? ab[e] : mxb;
  for (int off = 32; off; off >>= 1) {
    unsigned o = (unsigned)__shfl_down((int)mxb, off);
    mxb = o > mxb ? o : mxb;
  }
  mxb = (unsigned)__shfl((int)mxb, 0);
  const int emax = (int)(mxb >> 23);

  int eStar = 0, cntAbove = 0;
  {
    int prevc = 0;
    for (int e = emax; e >= 0; --e) {
      unsigned T = ((unsigned)e) << 23;
      int c = 0;
#pragma unroll
      for (int k = 0; k < 32; ++k) c += (ab[k] >= T) ? 1 : 0;
      for (int off = 32; off; off >>= 1) c += __shfl_down(c, off);
      c = __shfl(c, 0);
      if (c >= 50) { eStar = e; cntAbove = prevc; break; }
      prevc = c;
    }
  }
  unsigned kth = ((unsigned)eStar) << 23;
  int kneed = 50 - cntAbove;

  __shared__ int hist[256];
  __shared__ int sh_sel, sh_kneed;
  for (int p = 0; p < 3; ++p) {
    const unsigned mask = (p==0) ? 0x7F800000u : (p==1) ? 0x7FFF8000u : 0x7FFFFF80u;
    const int sh = (p==0) ? 15 : (p==1) ? 7 : 0;
    for (int t = lane; t < 256; t += 64) hist[t] = 0;
    __syncthreads();
#pragma unroll
    for (int e = 0; e < 32; ++e)
      if ((ab[e] & mask) == kth) atomicAdd(&hist[(ab[e] >> sh) & 0xFF], 1);
    __syncthreads();
    int h0 = hist[lane*4+0], h1 = hist[lane*4+1], h2 = hist[lane*4+2], h3 = hist[lane*4+3];
    int s = h0 + h1 + h2 + h3;
    int x = s;
    for (int off = 1; off < 64; off <<= 1) {
      int y = __shfl_down(x, off);
      if (lane + off < 64) x += y;
    }
    int excl = x - s;
    int c3 = excl + h3, c2 = c3 + h2, c1 = c2 + h1, c0 = c1 + h0;
    if (c0 >= kneed && c1   < kneed) { sh_sel = lane*4+0; sh_kneed = kneed - c1;  }
    if (c1 >= kneed && c2   < kneed) { sh_sel = lane*4+1; sh_kneed = kneed - c2;  }
    if (c2 >= kneed && c3   < kneed) { sh_sel = lane*4+2; sh_kneed = kneed - c3;  }
    if (c3 >= kneed && excl < kneed) { sh_sel = lane*4+3; sh_kneed = kneed - excl;}
    __syncthreads();
    kth |= ((unsigned)sh_sel) << sh;
    kneed = sh_kneed;
    __syncthreads();
  }

  int base = 0;
#pragma unroll
  for (int e4 = 0; e4 < 8; ++e4) {
    float o[4];
#pragma unroll
    for (int qq = 0; qq < 4; ++qq) {
      const int e = e4*4 + qq;
      const bool sel = ab[e] >= kth;
      unsigned long long msk = __ballot(sel);
      int pre = __popcll(msk & ((1ull << lane) - 1ull));
      const unsigned gi = (unsigned)(e4*256 + lane*4 + qq);
      if (sel) {
        int slot = base + pre;
        if (slot < 64) { sidx[b*64+slot] = gi; sval[b*64+slot] = v[e]; }
        if (finalMode) atomicAdd(&mD[gi & 1023u], v[e]*v[e]);
      }
      base += __popcll(msk);
      o[qq] = sel ? v[e] : 0.f;
    }
    if (finalMode) {
      float4 t = {o[0],o[1],o[2],o[3]};
      *(float4*)&dense[(size_t)b*DD + e4*256 + lane*4] = t;
    }
  }
  if (lane == 0) scnt[b] = base < 64 ? base : 64;
}

// ---------------------------------------------- fused spapply + topk (1 row)
__global__ __launch_bounds__(256)
void listep_kernel(const float* __restrict__ M, const float* __restrict__ baseB,
                   unsigned* __restrict__ sidx, float* __restrict__ sval,
                   int* __restrict__ scnt, float* __restrict__ dense,
                   float* __restrict__ mD, int finalMode) {
  const int b = blockIdx.x, tid = threadIdx.x;
  const int w = tid >> 6, lane = tid & 63;
  __shared__ unsigned si[64]; __shared__ float sv[64]; __shared__ int snc;
  __shared__ int hist[256];
  __shared__ unsigned redu[4]; __shared__ int redi[8];
  __shared__ int sh_sel, sh_kneed;
  if (tid < 64) { si[tid] = sidx[b*64+tid]; sv[tid] = sval[b*64+tid]; }
  if (tid == 0) snc = scnt[b];
  __syncthreads();
  const int nc = snc;
  const size_t o4 = (size_t)b * 512 + tid;
  float4 a0 = ((const float4*)baseB)[o4];
  float4 a1 = ((const float4*)baseB)[o4 + 256];
  int t = 0;
  for (; t + 2 <= nc; t += 2) {
    unsigned j0 = si[t], j1 = si[t+1];
    float v0 = sv[t], v1 = sv[t+1];
    const float4* r0 = (const float4*)(M + (size_t)j0 * DD);
    const float4* r1 = (const float4*)(M + (size_t)j1 * DD);
    float4 m00 = r0[tid], m01 = r0[tid + 256];
    float4 m10 = r1[tid], m11 = r1[tid + 256];
    a0.x = fmaf(v0, m00.x, a0.x); a0.y = fmaf(v0, m00.y, a0.y);
    a0.z = fmaf(v0, m00.z, a0.z); a0.w = fmaf(v0, m00.w, a0.w);
    a1.x = fmaf(v0, m01.x, a1.x); a1.y = fmaf(v0, m01.y, a1.y);
    a1.z = fmaf(v0, m01.z, a1.z); a1.w = fmaf(v0, m01.w, a1.w);
    a0.x = fmaf(v1, m10.x, a0.x); a0.y = fmaf(v1, m10.y, a0.y);
    a0.z = fmaf(v1, m10.z, a0.z); a0.w = fmaf(v1, m10.w, a0.w);
    a1.x = fmaf(v1, m11.x, a1.x); a1.y = fmaf(v1, m11.y, a1.y);
    a1.z = fmaf(v1, m11.z, a1.z); a1.w = fmaf(v1, m11.w, a1.w);
  }
  if (t < nc) {
    unsigned j0 = si[t]; float v0 = sv[t];
    const float4* r0 = (const float4*)(M + (size_t)j0 * DD);
    float4 m00 = r0[tid], m01 = r0[tid + 256];
    a0.x = fmaf(v0, m00.x, a0.x); a0.y = fmaf(v0, m00.y, a0.y);
    a0.z = fmaf(v0, m00.z, a0.z); a0.w = fmaf(v0, m00.w, a0.w);
    a1.x = fmaf(v0, m01.x, a1.x); a1.y = fmaf(v0, m01.y, a1.y);
    a1.z = fmaf(v0, m01.z, a1.z); a1.w = fmaf(v0, m01.w, a1.w);
  }
  float v0a[4] = {a0.x, a0.y, a0.z, a0.w};
  float v1a[4] = {a1.x, a1.y, a1.z, a1.w};
  unsigned ab0[4], ab1[4];
#pragma unroll
  for (int q = 0; q < 4; ++q) {
    ab0[q] = __float_as_uint(v0a[q]) & 0x7fffffffu;
    ab1[q] = __float_as_uint(v1a[q]) & 0x7fffffffu;
  }
  unsigned mx = 0;
#pragma unroll
  for (int q = 0; q < 4; ++q) {
    mx = ab0[q] > mx ? ab0[q] : mx;
    mx = ab1[q] > mx ? ab1[q] : mx;
  }
  for (int off = 32; off; off >>= 1) {
    unsigned o = (unsigned)__shfl_down((int)mx, off);
    mx = o > mx ? o : mx;
  }
  if (lane == 0) redu[w] = mx;
  __syncthreads();
  mx = redu[0];
  mx = redu[1] > mx ? redu[1] : mx;
  mx = redu[2] > mx ? redu[2] : mx;
  mx = redu[3] > mx ? redu[3] : mx;
  const int emax = (int)(mx >> 23);

  int eStar = 0, cntAbove = 0;
  {
    int prevc = 0;
    for (int e = emax; e >= 0; --e) {
      unsigned T = ((unsigned)e) << 23;
      int c = 0;
#pragma unroll
      for (int q = 0; q < 4; ++q) {
        c += (ab0[q] >= T) ? 1 : 0;
        c += (ab1[q] >= T) ? 1 : 0;
      }
      for (int off = 32; off; off >>= 1) c += __shfl_down(c, off);
      if (lane == 0) redi[w] = c;
      __syncthreads();
      c = redi[0] + redi[1] + redi[2] + redi[3];
      __syncthreads();
      if (c >= 50) { eStar = e; cntAbove = prevc; break; }
      prevc = c;
    }
  }
  unsigned kth = ((unsigned)eStar) << 23;
  int kneed = 50 - cntAbove;

  for (int p = 0; p < 3; ++p) {
    const unsigned mask = (p==0) ? 0x7F800000u : (p==1) ? 0x7FFF8000u : 0x7FFFFF80u;
    const int sh = (p==0) ? 15 : (p==1) ? 7 : 0;
    hist[tid] = 0;
    __syncthreads();
#pragma unroll
    for (int q = 0; q < 4; ++q) {
      if ((ab0[q] & mask) == kth) atomicAdd(&hist[(ab0[q] >> sh) & 0xFF], 1);
      if ((ab1[q] & mask) == kth) atomicAdd(&hist[(ab1[q] >> sh) & 0xFF], 1);
    }
    __syncthreads();
    if (w == 0) {
      int h0 = hist[lane*4+0], h1 = hist[lane*4+1], h2 = hist[lane*4+2], h3 = hist[lane*4+3];
      int s = h0 + h1 + h2 + h3;
      int x = s;
      for (int off = 1; off < 64; off <<= 1) {
        int y = __shfl_down(x, off);
        if (lane + off < 64) x += y;
      }
      int excl = x - s;
      int c3 = excl + h3, c2 = c3 + h2, c1 = c2 + h1, c0 = c1 + h0;
      if (c0 >= kneed && c1   < kneed) { sh_sel = lane*4+0; sh_kneed = kneed - c1;  }
      if (c1 >= kneed && c2   < kneed) { sh_sel = lane*4+1; sh_kneed = kneed - c2;  }
      if (c2 >= kneed && c3   < kneed) { sh_sel = lane*4+2; sh_kneed = kneed - c3;  }
      if (c3 >= kneed && excl < kneed) { sh_sel = lane*4+3; sh_kneed = kneed - excl;}
    }
    __syncthreads();
    kth |= ((unsigned)sh_sel) << sh;
    kneed = sh_kneed;
    __syncthreads();
  }

  unsigned long long m0q[4], m1q[4];
  int q0pre[4], q1pre[4], c0 = 0, c1 = 0;
#pragma unroll
  for (int q = 0; q < 4; ++q) {
    m0q[q] = __ballot(ab0[q] >= kth);
    q0pre[q] = c0; c0 += __popcll(m0q[q]);
  }
#pragma unroll
  for (int q = 0; q < 4; ++q) {
    m1q[q] = __ballot(ab1[q] >= kth);
    q1pre[q] = c1; c1 += __popcll(m1q[q]);
  }
  if (lane == 0) { redi[w] = c0; redi[4 + w] = c1; }
  __syncthreads();
  int bs[8]; int run = 0;
#pragma unroll
  for (int c = 0; c < 8; ++c) { bs[c] = run; run += redi[c]; }
  const int total = run;
  const unsigned long long ltm = (1ull << lane) - 1ull;
  float o0[4], o1[4];
#pragma unroll
  for (int q = 0; q < 4; ++q) {
    const bool sel = ab0[q] >= kth;
    if (sel) {
      int slot = bs[w] + q0pre[q] + __popcll(m0q[q] & ltm);
      const unsigned gi = (unsigned)(tid*4 + q);
      if (slot < 64) { sidx[b*64+slot] = gi; sval[b*64+slot] = v0a[q]; }
      if (finalMode) atomicAdd(&mD[gi & 1023u], v0a[q]*v0a[q]);
    }
    o0[q] = sel ? v0a[q] : 0.f;
  }
#pragma unroll
  for (int q = 0; q < 4; ++q) {
    const bool sel = ab1[q] >= kth;
    if (sel) {
      int slot = bs[4 + w] + q1pre[q] + __popcll(m1q[q] & ltm);
      const unsigned gi = (unsigned)(1024 + tid*4 + q);
      if (slot < 64) { sidx[b*64+slot] = gi; sval[b*64+slot] = v1a[q]; }
      if (finalMode) atomicAdd(&mD[gi & 1023u], v1a[q]*v1a[q]);
    }
    o1[q] = sel ? v1a[q] : 0.f;
  }
  if (finalMode) {
    float4 t0 = {o0[0], o0[1], o0[2], o0[3]};
    float4 t1 = {o1[0], o1[1], o1[2], o1[3]};
    ((float4*)dense)[o4] = t0;
    ((float4*)dense)[o4 + 256] = t1;
  }
  if (tid == 0) scnt[b] = total < 64 ? total : 64;
}

// -------------------------------------------- sparse apply (dense out, no base)
__global__ __launch_bounds__(256)
void spapply2(const float* __restrict__ M, float* __restrict__ outF,
              const unsigned* __restrict__ sidx, const float* __restrict__ sval,
              const int* __restrict__ scnt) {
  const int b = blockIdx.x, tid = threadIdx.x;
  __shared__ unsigned si[64]; __shared__ float sv[64]; __shared__ int snc;
  if (tid < 64) { si[tid] = sidx[b*64+tid]; sv[tid] = sval[b*64+tid]; }
  if (tid == 0) snc = scnt[b];
  __syncthreads();
  const int nc = snc;
  const size_t o4 = (size_t)b * 512 + tid;
  float4 a0 = make_float4(0.f,0.f,0.f,0.f);
  float4 a1 = make_float4(0.f,0.f,0.f,0.f);
  int t = 0;
  for (; t + 2 <= nc; t += 2) {
    unsigned j0 = si[t], j1 = si[t+1];
    float v0 = sv[t], v1 = sv[t+1];
    const float4* r0 = (const float4*)(M + (size_t)j0 * DD);
    const float4* r1 = (const float4*)(M + (size_t)j1 * DD);
    float4 m00 = r0[tid], m01 = r0[tid + 256];
    float4 m10 = r1[tid], m11 = r1[tid + 256];
    a0.x = fmaf(v0, m00.x, a0.x); a0.y = fmaf(v0, m00.y, a0.y);
    a0.z = fmaf(v0, m00.z, a0.z); a0.w = fmaf(v0, m00.w, a0.w);
    a1.x = fmaf(v0, m01.x, a1.x); a1.y = fmaf(v0, m01.y, a1.y);
    a1.z = fmaf(v0, m01.z, a1.z); a1.w = fmaf(v0, m01.w, a1.w);
    a0.x = fmaf(v1, m10.x, a0.x); a0.y = fmaf(v1, m10.y, a0.y);
    a0.z = fmaf(v1, m10.z, a0.z); a0.w = fmaf(v1, m10.w, a0.w);
    a1.x = fmaf(v1, m11.x, a1.x); a1.y = fmaf(v1, m11.y, a1.y);
    a1.z = fmaf(v1, m11.z, a1.z); a1.w = fmaf(v1, m11.w, a1.w);
  }
  if (t < nc) {
    unsigned j0 = si[t]; float v0 = sv[t];
    const float4* r0 = (const float4*)(M + (size_t)j0 * DD);
    float4 m00 = r0[tid], m01 = r0[tid + 256];
    a0.x = fmaf(v0, m00.x, a0.x); a0.y = fmaf(v0, m00.y, a0.y);
    a0.z = fmaf(v0, m00.z, a0.z); a0.w = fmaf(v0, m00.w, a0.w);
    a1.x = fmaf(v0, m01.x, a1.x); a1.y = fmaf(v0, m01.y, a1.y);
    a1.z = fmaf(v0, m01.z, a1.z); a1.w = fmaf(v0, m01.w, a1.w);
  }
  ((float4*)outF)[o4] = a0;
  ((float4*)outF)[o4 + 256] = a1;
}

// ------------------------------------------------------------- attention bits
__global__ __launch_bounds__(256)
void attdot_kernel(const float* __restrict__ prev, const float* __restrict__ U,
                   float* __restrict__ att) {
  const int b = blockIdx.x, p = blockIdx.y, tid = threadIdx.x;
  const float* pr = prev + ((size_t)p*NB + b) * DD;
  const float* u  = U + (size_t)b * DD;
  float s = 0.f;
#pragma unroll
  for (int h = 0; h < 2; ++h) {
    int i = (tid + h*256) * 4;
    float4 a = *(const float4*)&pr[i];
    float4 c = *(const float4*)&u[i];
    s += a.x*c.x + a.y*c.y + a.z*c.z + a.w*c.w;
  }
  for (int off = 32; off; off >>= 1) s += __shfl_down(s, off);
  __shared__ float ps[4];
  if ((tid & 63) == 0) ps[tid >> 6] = s;
  __syncthreads();
  if (tid == 0) att[(size_t)p*NB + b] = ps[0]+ps[1]+ps[2]+ps[3];
}

__global__ __launch_bounds__(256)
void softmax_kernel(const float* __restrict__ att, float* __restrict__ attw) {
  const int p = blockIdx.x, tid = threadIdx.x;
  const float* a = att + (size_t)p*NB;
  float loc[8]; float mx = -3.4e38f;
#pragma unroll
  for (int h = 0; h < 8; ++h) { loc[h] = a[tid + h*256]; mx = fmaxf(mx, loc[h]); }
  for (int off = 32; off; off >>= 1) mx = fmaxf(mx, __shfl_down(mx, off));
  __shared__ float ps[4]; __shared__ float sh_m, sh_s;
  if ((tid & 63) == 0) ps[tid >> 6] = mx;
  __syncthreads();
  if (tid == 0) sh_m = fmaxf(fmaxf(ps[0],ps[1]), fmaxf(ps[2],ps[3]));
  __syncthreads();
  const float m = sh_m;
  float sum = 0.f;
#pragma unroll
  for (int h = 0; h < 8; ++h) sum += expf(loc[h] - m);
  for (int off = 32; off; off >>= 1) sum += __shfl_down(sum, off);
  __syncthreads();
  if ((tid & 63) == 0) ps[tid >> 6] = sum;
  __syncthreads();
  if (tid == 0) sh_s = ps[0]+ps[1]+ps[2]+ps[3];
  __syncthreads();
  const float inv = 1.0f / sh_s;
#pragma unroll
  for (int h = 0; h < 8; ++h) attw[(size_t)p*NB + tid + h*256] = expf(loc[h] - m) * inv;
}

__global__ __launch_bounds__(256)
void zatt_kernel(const float* __restrict__ prev, const float* __restrict__ attw,
                 const float* __restrict__ lam, float* __restrict__ Z) {
  const int b = blockIdx.x, tid = threadIdx.x;
  __shared__ float w[8];
  if (tid < 8) w[tid] = attw[(size_t)tid*NB + b];
  __syncthreads();
  const float l2 = lam[0];
#pragma unroll
  for (int h = 0; h < 2; ++h) {
    int i = (tid + h*256) * 4;
    float4 acc = {0.f,0.f,0.f,0.f};
#pragma unroll
    for (int p = 0; p < 8; ++p) {
      float4 pv = *(const float4*)&prev[((size_t)p*NB + b)*DD + i];
      float wp = w[p];
      acc.x += wp * fminf(fmaxf(pv.x, -150.f), 150.f);
      acc.y += wp * fminf(fmaxf(pv.y, -150.f), 150.f);
      acc.z += wp * fminf(fmaxf(pv.z, -150.f), 150.f);
      acc.w += wp * fminf(fmaxf(pv.w, -150.f), 150.f);
    }
    acc.x *= l2; acc.y *= l2; acc.z *= l2; acc.w *= l2;
    *(float4*)&Z[(size_t)b*DD + i] = acc;
  }
}

__global__ __launch_bounds__(256)
void norm_kernel(float* __restrict__ mD) {
  const int tid = threadIdx.x;
  float v[4]; float mn = 3.4e38f, mx = -3.4e38f;
#pragma unroll
  for (int h = 0; h < 4; ++h) {
    v[h] = mD[tid + h*256];
    mn = fminf(mn, v[h]); mx = fmaxf(mx, v[h]);
  }
  for (int off = 32; off; off >>= 1) {
    mn = fminf(mn, __shfl_down(mn, off));
    mx = fmaxf(mx, __shfl_down(mx, off));
  }
  __shared__ float pmn[4], pmx[4]; __shared__ float smn, smx;
  if ((tid & 63) == 0) { pmn[tid>>6] = mn; pmx[tid>>6] = mx; }
  __syncthreads();
  if (tid == 0) {
    smn = fminf(fminf(pmn[0],pmn[1]), fminf(pmn[2],pmn[3]));
    smx = fmaxf(fmaxf(pmx[0],pmx[1]), fmaxf(pmx[2],pmx[3]));
  }
  __syncthreads();
  const float d = smx - smn + 1e-8f;
#pragma unroll
  for (int h = 0; h < 4; ++h) mD[tid + h*256] = (v[h] - smn) / d;
}

// ----------------------------------------------------------------- launcher
extern "C" void kernel_launch(void* const* d_in, const int* in_sizes, int n_in,
                              void* d_out, int out_size, void* d_ws, size_t ws_size,
                              hipStream_t stream) {
  const float* x    = (const float*)d_in[0];   // (2048, 2048)
  const float* prev = (const float*)d_in[1];   // (8, 2048, 2048)
  const float* Wd   = (const float*)d_in[2];   // (2048, 2048)
  const float* S    = (const float*)d_in[3];   // (2048, 2048) symmetric
  const float* lam  = (const float*)d_in[4];   // scalar

  float* out   = (float*)d_out;
  float* mD    = out;
  float* zlast = out + 1024;

  float* B  = (float*)d_ws;                       // 16 MB
  float* C  = B  + (1u << 22);                    // 16 MB (WdT early, C later)
  float* X1 = C  + (1u << 22);                    // 16 MB
  unsigned* sidx = (unsigned*)(X1 + (1u << 22));
  float*    sval = (float*)(sidx + 2048*64);
  int*      scnt = (int*)(sval + 2048*64);
  float*    att  = (float*)(scnt + 2048);
  float*    attw = att + 8*2048;
  float*    U    = zlast;

  const dim3 gGemm(DD/64, DD/64);     // (32, 32) = 1024 blocks (4/CU)

  // WdT = Wd^T  (so GEMM1 is NN with n-contiguous B)
  wtrans<<<dim3(64, 64), 256, 0, stream>>>(Wd, C);
  // B = x @ Wd^T  = x @ WdT(NN)
  gemm_sb<0><<<gGemm, 256, 0, stream>>>(x, C, nullptr, B);
  // z1 = hard_thr(B)
  topk_kernel<<<NB, 64, 0, stream>>>(B, sidx, sval, scnt, nullptr, nullptr, 0);
  // z2 = hard_thr(B + S z1)   (fused)
  listep_kernel<<<NB, 256, 0, stream>>>(S, B, sidx, sval, scnt, nullptr, nullptr, 0);
  // s_t = Wd^T z2  (sparse rows of Wd)
  spapply2<<<NB, 256, 0, stream>>>(Wd, X1, sidx, sval, scnt);
  // u = s_t @ Wd  (NN)
  gemm_sb<0><<<gGemm, 256, 0, stream>>>(X1, Wd, nullptr, U);
  // att / softmax / z_att
  attdot_kernel<<<dim3(NB, 8), 256, 0, stream>>>(prev, U, att);
  softmax_kernel<<<8, 256, 0, stream>>>(att, attw);
  zatt_kernel<<<NB, 256, 0, stream>>>(prev, attw, lam, X1);
  // iter 1 (dense z): C = B + z_att @ S  (NN; S symmetric; overwrites WdT)
  gemm_sb<1><<<gGemm, 256, 0, stream>>>(X1, S, B, C);
  topk_kernel<<<NB, 64, 0, stream>>>(C, sidx, sval, scnt, nullptr, nullptr, 0);
  for (int it = 1; it < 10; ++it) {
    const int fin = (it == 9);
    if (fin) hipMemsetAsync(mD, 0, 1024 * sizeof(float), stream);
    listep_kernel<<<NB, 256, 0, stream>>>(S, B, sidx, sval, scnt,
                                          fin ? zlast : nullptr,
                                          fin ? mD : nullptr, fin);
  }
  norm_kernel<<<1, 256, 0, stream>>>(mD);
}

// Round 7
// 1569.831 us; speedup vs baseline: 1.2894x; 1.1668x over previous
//
#include <hip/hip_runtime.h>

// DUST_65085934403760 : LIHT sparse-coding + window attention, MI355X fp32.
// D=2048, BATCH=2048, P=8, OMEGA=50, 10 iters, L=1, CLAMP=150.
// Round 7 (numerics bit-identical to rounds 1/3/4/5/6):
//  - gemm_f32: round-3 kernel verbatim (best measured fp32 GEMM, 251 us).
//  - spapply_sl: XCD-sliced sparse apply. Grid (8, 2048): blockIdx.x = column
//    slice of 256 cols; linear id = slice + 8*row -> round-robin dispatch maps
//    slice s to XCD s for every row, so each XCD's 4MB L2 holds only its 2MB
//    slice of S -> gather becomes L2-resident instead of L3 (819 MB/iter).
//    Chain: base-first + ascending-t single fma chain = bit-identical.
//  - topk_kernel: round-3 proven kernel (canonical slot order).

#define DD 2048
#define NB 2048

// ------------------------------------------------------------- GEMM (fp32)
// C[m,n] = sum_k A[m,k] * (TRANSB ? Bm[n,k] : Bm[k,n])  (+ Cadd[m,n] at end)
// Tile 128(m) x 64(n), k-chunk 16, 256 threads, 8x4 outputs/thread.
template<int TRANSB, int ADD>
__global__ __launch_bounds__(256)
void gemm_f32(const float* __restrict__ A, const float* __restrict__ Bm,
              const float* __restrict__ Cadd, float* __restrict__ Cout) {
  __shared__ float As[2][16][132];   // [k][m], padded
  __shared__ float Bs[2][16][68];    // [k][n], padded
  const int tid = threadIdx.x;
  const int m0 = blockIdx.y * 128, n0 = blockIdx.x * 64;
  const int lr = tid >> 1, lk = (tid & 1) * 8;
  const int br  = tid >> 2, bk1 = (tid & 3) * 4;   // TRANSB=1: 64 rows x 16 k
  const int bk0 = tid >> 4, bn  = (tid & 15) * 4;  // TRANSB=0: 16 rows x 64 n
  const int ty = tid >> 4, tx = tid & 15;          // output: m=ty*8+, n=tx*4+

  float acc[8][4];
#pragma unroll
  for (int i = 0; i < 8; ++i)
#pragma unroll
    for (int j = 0; j < 4; ++j) acc[i][j] = 0.f;

  const float* Arow = A + (size_t)(m0 + lr) * DD + lk;
  const float* Bp = TRANSB ? (Bm + (size_t)(n0 + br) * DD + bk1)
                           : (Bm + (size_t)bk0 * DD + n0 + bn);

  float4 a0 = *(const float4*)(Arow);
  float4 a1 = *(const float4*)(Arow + 4);
  float4 bv = *(const float4*)(Bp);

  {
    As[0][lk+0][lr]=a0.x; As[0][lk+1][lr]=a0.y; As[0][lk+2][lr]=a0.z; As[0][lk+3][lr]=a0.w;
    As[0][lk+4][lr]=a1.x; As[0][lk+5][lr]=a1.y; As[0][lk+6][lr]=a1.z; As[0][lk+7][lr]=a1.w;
    if (TRANSB) {
      Bs[0][bk1+0][br]=bv.x; Bs[0][bk1+1][br]=bv.y; Bs[0][bk1+2][br]=bv.z; Bs[0][bk1+3][br]=bv.w;
    } else {
      *(float4*)&Bs[0][bk0][bn] = bv;
    }
  }
  __syncthreads();

  const int NC = DD / 16;
  for (int c = 0; c < NC; ++c) {
    const int buf = c & 1;
    if (c + 1 < NC) {
      const int k1 = (c + 1) * 16;
      a0 = *(const float4*)(Arow + k1);
      a1 = *(const float4*)(Arow + k1 + 4);
      bv = TRANSB ? *(const float4*)(Bp + k1)
                  : *(const float4*)(Bp + (size_t)k1 * DD);
    }
#pragma unroll
    for (int kk = 0; kk < 16; ++kk) {
      float4 av0 = *(const float4*)&As[buf][kk][ty*8];
      float4 av1 = *(const float4*)&As[buf][kk][ty*8+4];
      float4 bq  = *(const float4*)&Bs[buf][kk][tx*4];
      float a[8]  = {av0.x,av0.y,av0.z,av0.w,av1.x,av1.y,av1.z,av1.w};
      float bb[4] = {bq.x,bq.y,bq.z,bq.w};
#pragma unroll
      for (int i = 0; i < 8; ++i)
#pragma unroll
        for (int j = 0; j < 4; ++j)
          acc[i][j] = fmaf(a[i], bb[j], acc[i][j]);
    }
    if (c + 1 < NC) {
      const int nb = buf ^ 1;
      __syncthreads();
      As[nb][lk+0][lr]=a0.x; As[nb][lk+1][lr]=a0.y; As[nb][lk+2][lr]=a0.z; As[nb][lk+3][lr]=a0.w;
      As[nb][lk+4][lr]=a1.x; As[nb][lk+5][lr]=a1.y; As[nb][lk+6][lr]=a1.z; As[nb][lk+7][lr]=a1.w;
      if (TRANSB) {
        Bs[nb][bk1+0][br]=bv.x; Bs[nb][bk1+1][br]=bv.y; Bs[nb][bk1+2][br]=bv.z; Bs[nb][bk1+3][br]=bv.w;
      } else {
        *(float4*)&Bs[nb][bk0][bn] = bv;
      }
      __syncthreads();
    }
  }

#pragma unroll
  for (int i = 0; i < 8; ++i) {
    size_t row = (size_t)(m0 + ty*8 + i) * DD + n0 + tx*4;
    float4 c0 = {acc[i][0], acc[i][1], acc[i][2], acc[i][3]};
    if (ADD) {
      float4 d0 = *(const float4*)&Cadd[row];
      c0.x += d0.x; c0.y += d0.y; c0.z += d0.z; c0.w += d0.w;
    }
    *(float4*)&Cout[row] = c0;
  }
}

// ------------------------------------ XCD-sliced sparse apply (1 wave/block)
// grid (8, NB): blockIdx.x = 256-col slice (-> XCD via round-robin), .y = row.
// out[b, cols] = (HASBASE ? base : 0) + sum_t sval[t] * M[sidx[t], cols]
// Base-first, ascending-t single fma chain (bit-identical to round-3 chain).
template<int HASBASE>
__global__ __launch_bounds__(64)
void spapply_sl(const float* __restrict__ M, const float* __restrict__ baseB,
                float* __restrict__ outF, const unsigned* __restrict__ sidx,
                const float* __restrict__ sval, const int* __restrict__ scnt) {
  const int b = blockIdx.y, lane = threadIdx.x;
  const int col = blockIdx.x * 256 + lane * 4;
  const int nc = scnt[b];
  const unsigned* ip = sidx + b * 64;
  const float* vp = sval + b * 64;
  const size_t ro = (size_t)b * DD + col;
  float4 a;
  if (HASBASE) a = *(const float4*)&baseB[ro];
  else         a = make_float4(0.f, 0.f, 0.f, 0.f);
  for (int t = 0; t < nc; ++t) {
    const unsigned j = ip[t];
    const float v = vp[t];
    float4 m = *(const float4*)&M[(size_t)j * DD + col];
    a.x = fmaf(v, m.x, a.x); a.y = fmaf(v, m.y, a.y);
    a.z = fmaf(v, m.z, a.z); a.w = fmaf(v, m.w, a.w);
  }
  *(float4*)&outF[ro] = a;
}

// ------------------------------------------------------------ top-k (1 wave)
// Round-3 proven kernel, verbatim (canonical slot order).
__global__ __launch_bounds__(64)
void topk_kernel(const float* __restrict__ src, unsigned* __restrict__ sidx,
                 float* __restrict__ sval, int* __restrict__ scnt,
                 float* __restrict__ dense, float* __restrict__ mD,
                 int finalMode) {
  const int b = blockIdx.x;
  const int lane = threadIdx.x;
  const float* row = src + (size_t)b * DD;
  float v[32]; unsigned ab[32];
#pragma unroll
  for (int e4 = 0; e4 < 8; ++e4) {
    float4 t = *(const float4*)&row[e4*256 + lane*4];
    v[e4*4+0]=t.x; v[e4*4+1]=t.y; v[e4*4+2]=t.z; v[e4*4+3]=t.w;
  }
#pragma unroll
  for (int e = 0; e < 32; ++e) ab[e] = __float_as_uint(v[e]) & 0x7fffffffu;

  unsigned mxb = 0;
#pragma unroll
  for (int e = 0; e < 32; ++e) mxb = ab[e] > mxb ? ab[e] : mxb;
  for (int off = 32; off; off >>= 1) {
    unsigned o = (unsigned)__shfl_down((int)mxb, off);
    mxb = o > mxb ? o : mxb;
  }
  mxb = (unsigned)__shfl((int)mxb, 0);
  const int emax = (int)(mxb >> 23);

  int eStar = 0, cntAbove = 0;
  {
    int prevc = 0;
    for (int e = emax; e >= 0; --e) {
      unsigned T = ((unsigned)e) << 23;
      int c = 0;
#pragma unroll
      for (int k = 0; k < 32; ++k) c += (ab[k] >= T) ? 1 : 0;
      for (int off = 32; off; off >>= 1) c += __shfl_down(c, off);
      c = __shfl(c, 0);
      if (c >= 50) { eStar = e; cntAbove = prevc; break; }
      prevc = c;
    }
  }
  unsigned kth = ((unsigned)eStar) << 23;
  int kneed = 50 - cntAbove;

  __shared__ int hist[256];
  __shared__ int sh_sel, sh_kneed;
  for (int p = 0; p < 3; ++p) {
    const unsigned mask = (p==0) ? 0x7F800000u : (p==1) ? 0x7FFF8000u : 0x7FFFFF80u;
    const int sh = (p==0) ? 15 : (p==1) ? 7 : 0;
    for (int t = lane; t < 256; t += 64) hist[t] = 0;
    __syncthreads();
#pragma unroll
    for (int e = 0; e < 32; ++e)
      if ((ab[e] & mask) == kth) atomicAdd(&hist[(ab[e] >> sh) & 0xFF], 1);
    __syncthreads();
    int h0 = hist[lane*4+0], h1 = hist[lane*4+1], h2 = hist[lane*4+2], h3 = hist[lane*4+3];
    int s = h0 + h1 + h2 + h3;
    int x = s;
    for (int off = 1; off < 64; off <<= 1) {
      int y = __shfl_down(x, off);
      if (lane + off < 64) x += y;
    }
    int excl = x - s;
    int c3 = excl + h3, c2 = c3 + h2, c1 = c2 + h1, c0 = c1 + h0;
    if (c0 >= kneed && c1   < kneed) { sh_sel = lane*4+0; sh_kneed = kneed - c1;  }
    if (c1 >= kneed && c2   < kneed) { sh_sel = lane*4+1; sh_kneed = kneed - c2;  }
    if (c2 >= kneed && c3   < kneed) { sh_sel = lane*4+2; sh_kneed = kneed - c3;  }
    if (c3 >= kneed && excl < kneed) { sh_sel = lane*4+3; sh_kneed = kneed - excl;}
    __syncthreads();
    kth |= ((unsigned)sh_sel) << sh;
    kneed = sh_kneed;
    __syncthreads();
  }

  int base = 0;
#pragma unroll
  for (int e4 = 0; e4 < 8; ++e4) {
    float o[4];
#pragma unroll
    for (int qq = 0; qq < 4; ++qq) {
      const int e = e4*4 + qq;
      const bool sel = ab[e] >= kth;
      unsigned long long msk = __ballot(sel);
      int pre = __popcll(msk & ((1ull << lane) - 1ull));
      const unsigned gi = (unsigned)(e4*256 + lane*4 + qq);
      if (sel) {
        int slot = base + pre;
        if (slot < 64) { sidx[b*64+slot] = gi; sval[b*64+slot] = v[e]; }
        if (finalMode) atomicAdd(&mD[gi & 1023u], v[e]*v[e]);
      }
      base += __popcll(msk);
      o[qq] = sel ? v[e] : 0.f;
    }
    if (finalMode) {
      float4 t = {o[0],o[1],o[2],o[3]};
      *(float4*)&dense[(size_t)b*DD + e4*256 + lane*4] = t;
    }
  }
  if (lane == 0) scnt[b] = base < 64 ? base : 64;
}

// ------------------------------------------------------------- attention bits
__global__ __launch_bounds__(256)
void attdot_kernel(const float* __restrict__ prev, const float* __restrict__ U,
                   float* __restrict__ att) {
  const int b = blockIdx.x, p = blockIdx.y, tid = threadIdx.x;
  const float* pr = prev + ((size_t)p*NB + b) * DD;
  const float* u  = U + (size_t)b * DD;
  float s = 0.f;
#pragma unroll
  for (int h = 0; h < 2; ++h) {
    int i = (tid + h*256) * 4;
    float4 a = *(const float4*)&pr[i];
    float4 c = *(const float4*)&u[i];
    s += a.x*c.x + a.y*c.y + a.z*c.z + a.w*c.w;
  }
  for (int off = 32; off; off >>= 1) s += __shfl_down(s, off);
  __shared__ float ps[4];
  if ((tid & 63) == 0) ps[tid >> 6] = s;
  __syncthreads();
  if (tid == 0) att[(size_t)p*NB + b] = ps[0]+ps[1]+ps[2]+ps[3];
}

__global__ __launch_bounds__(256)
void softmax_kernel(const float* __restrict__ att, float* __restrict__ attw) {
  const int p = blockIdx.x, tid = threadIdx.x;
  const float* a = att + (size_t)p*NB;
  float loc[8]; float mx = -3.4e38f;
#pragma unroll
  for (int h = 0; h < 8; ++h) { loc[h] = a[tid + h*256]; mx = fmaxf(mx, loc[h]); }
  for (int off = 32; off; off >>= 1) mx = fmaxf(mx, __shfl_down(mx, off));
  __shared__ float ps[4]; __shared__ float sh_m, sh_s;
  if ((tid & 63) == 0) ps[tid >> 6] = mx;
  __syncthreads();
  if (tid == 0) sh_m = fmaxf(fmaxf(ps[0],ps[1]), fmaxf(ps[2],ps[3]));
  __syncthreads();
  const float m = sh_m;
  float sum = 0.f;
#pragma unroll
  for (int h = 0; h < 8; ++h) sum += expf(loc[h] - m);
  for (int off = 32; off; off >>= 1) sum += __shfl_down(sum, off);
  __syncthreads();
  if ((tid & 63) == 0) ps[tid >> 6] = sum;
  __syncthreads();
  if (tid == 0) sh_s = ps[0]+ps[1]+ps[2]+ps[3];
  __syncthreads();
  const float inv = 1.0f / sh_s;
#pragma unroll
  for (int h = 0; h < 8; ++h) attw[(size_t)p*NB + tid + h*256] = expf(loc[h] - m) * inv;
}

__global__ __launch_bounds__(256)
void zatt_kernel(const float* __restrict__ prev, const float* __restrict__ attw,
                 const float* __restrict__ lam, float* __restrict__ Z) {
  const int b = blockIdx.x, tid = threadIdx.x;
  __shared__ float w[8];
  if (tid < 8) w[tid] = attw[(size_t)tid*NB + b];
  __syncthreads();
  const float l2 = lam[0];
#pragma unroll
  for (int h = 0; h < 2; ++h) {
    int i = (tid + h*256) * 4;
    float4 acc = {0.f,0.f,0.f,0.f};
#pragma unroll
    for (int p = 0; p < 8; ++p) {
      float4 pv = *(const float4*)&prev[((size_t)p*NB + b)*DD + i];
      float wp = w[p];
      acc.x += wp * fminf(fmaxf(pv.x, -150.f), 150.f);
      acc.y += wp * fminf(fmaxf(pv.y, -150.f), 150.f);
      acc.z += wp * fminf(fmaxf(pv.z, -150.f), 150.f);
      acc.w += wp * fminf(fmaxf(pv.w, -150.f), 150.f);
    }
    acc.x *= l2; acc.y *= l2; acc.z *= l2; acc.w *= l2;
    *(float4*)&Z[(size_t)b*DD + i] = acc;
  }
}

__global__ __launch_bounds__(256)
void norm_kernel(float* __restrict__ mD) {
  const int tid = threadIdx.x;
  float v[4]; float mn = 3.4e38f, mx = -3.4e38f;
#pragma unroll
  for (int h = 0; h < 4; ++h) {
    v[h] = mD[tid + h*256];
    mn = fminf(mn, v[h]); mx = fmaxf(mx, v[h]);
  }
  for (int off = 32; off; off >>= 1) {
    mn = fminf(mn, __shfl_down(mn, off));
    mx = fmaxf(mx, __shfl_down(mx, off));
  }
  __shared__ float pmn[4], pmx[4]; __shared__ float smn, smx;
  if ((tid & 63) == 0) { pmn[tid>>6] = mn; pmx[tid>>6] = mx; }
  __syncthreads();
  if (tid == 0) {
    smn = fminf(fminf(pmn[0],pmn[1]), fminf(pmn[2],pmn[3]));
    smx = fmaxf(fmaxf(pmx[0],pmx[1]), fmaxf(pmx[2],pmx[3]));
  }
  __syncthreads();
  const float d = smx - smn + 1e-8f;
#pragma unroll
  for (int h = 0; h < 4; ++h) mD[tid + h*256] = (v[h] - smn) / d;
}

// ----------------------------------------------------------------- launcher
extern "C" void kernel_launch(void* const* d_in, const int* in_sizes, int n_in,
                              void* d_out, int out_size, void* d_ws, size_t ws_size,
                              hipStream_t stream) {
  const float* x    = (const float*)d_in[0];   // (2048, 2048)
  const float* prev = (const float*)d_in[1];   // (8, 2048, 2048)
  const float* Wd   = (const float*)d_in[2];   // (2048, 2048)
  const float* S    = (const float*)d_in[3];   // (2048, 2048) symmetric
  const float* lam  = (const float*)d_in[4];   // scalar

  float* out   = (float*)d_out;
  float* mD    = out;                 // 1024
  float* zlast = out + 1024;          // dense z_last; doubles as U scratch early

  float* B  = (float*)d_ws;                       // 16 MB
  float* C  = B  + (1u << 22);                    // 16 MB
  float* X1 = C  + (1u << 22);                    // 16 MB (s_t, then z_att)
  unsigned* sidx = (unsigned*)(X1 + (1u << 22));
  float*    sval = (float*)(sidx + 2048*64);
  int*      scnt = (int*)(sval + 2048*64);
  float*    att  = (float*)(scnt + 2048);
  float*    attw = att + 8*2048;
  float*    U    = zlast;

  const dim3 gGemm(DD/64, DD/128);    // 32 x 16 = 512 blocks (2/CU)
  const dim3 gSp(8, NB);              // slice-major: linear id % 8 = slice = XCD

  // B = x @ Wd^T
  gemm_f32<1,0><<<gGemm, 256, 0, stream>>>(x, Wd, nullptr, B);
  // z1 = hard_thr(B)
  topk_kernel<<<NB, 64, 0, stream>>>(B, sidx, sval, scnt, nullptr, nullptr, 0);
  // C = B + S z1   (XCD-sliced gather)
  spapply_sl<1><<<gSp, 64, 0, stream>>>(S, B, C, sidx, sval, scnt);
  // z2 = hard_thr(C)
  topk_kernel<<<NB, 64, 0, stream>>>(C, sidx, sval, scnt, nullptr, nullptr, 0);
  // s_t = Wd^T z2  (sparse rows of Wd, sliced)
  spapply_sl<0><<<gSp, 64, 0, stream>>>(Wd, nullptr, X1, sidx, sval, scnt);
  // u = s_t @ Wd
  gemm_f32<0,0><<<gGemm, 256, 0, stream>>>(X1, Wd, nullptr, U);
  // att[p,b] = <prev[p,b,:], u[b,:]>
  attdot_kernel<<<dim3(NB, 8), 256, 0, stream>>>(prev, U, att);
  softmax_kernel<<<8, 256, 0, stream>>>(att, attw);
  // z_att = lambda2 * sum_p attw * clip(prev)
  zatt_kernel<<<NB, 256, 0, stream>>>(prev, attw, lam, X1);
  // iter 1 (dense z): C = B + z_att @ S   (S symmetric)
  gemm_f32<0,1><<<gGemm, 256, 0, stream>>>(X1, S, B, C);
  topk_kernel<<<NB, 64, 0, stream>>>(C, sidx, sval, scnt, nullptr, nullptr, 0);
  // it 1..9: sliced gather + threshold; final emits dense z_last + mD
  for (int it = 1; it < 10; ++it) {
    spapply_sl<1><<<gSp, 64, 0, stream>>>(S, B, C, sidx, sval, scnt);
    const int fin = (it == 9);
    if (fin) hipMemsetAsync(mD, 0, 1024 * sizeof(float), stream);
    topk_kernel<<<NB, 64, 0, stream>>>(C, sidx, sval, scnt,
                                       fin ? zlast : nullptr,
                                       fin ? mD : nullptr, fin);
  }
  // mD_norm = (mD - min) / (max - min + 1e-8)
  norm_kernel<<<1, 256, 0, stream>>>(mD);
}